// Round 16
// baseline (255.280 us; speedup 1.0000x reference)
//
#include <hip/hip_runtime.h>
#include <hip/hip_bf16.h>
#include <stdint.h>

typedef __bf16 bf16_t;
typedef __bf16 bf16x8 __attribute__((ext_vector_type(8)));
typedef __bf16 bf16x4 __attribute__((ext_vector_type(4)));
typedef float f32x4 __attribute__((ext_vector_type(4)));

#define SCALING 0.125f
#define EXPBIAS 20.0f

// ws layout (byte offsets)
#define WS_XQ  (0u)         // [4096][1024] bf16 query
#define WS_W   (8u << 20)   // 4 x [1024][1024] bf16 (Wq,Wk,Wv,Wo)
#define WS_QH  (16u << 20)  // [32][2048][64] bf16  q*scale, head layout
#define WS_KH  (24u << 20)  // [32] fragment-major K (2048*64 bf16 per bh)
#define WS_VT  (32u << 20)  // [32] fragment-major V (2048*64 bf16 per bh)
#define WS_X2  (40u << 20)  // [4096][1024] bf16  attention head outputs
#define WS_AM  (48u << 20)  // 8.4 MB fragment-major amask (bf16, minus EXPBIAS)

// d_out offsets (float elements)
#define OFF_OUT 0
#define OFF_WEI 4194304
#define OFF_K   138412032
#define OFF_V   142606336

typedef const __attribute__((address_space(1))) void gvoid_t;
typedef __attribute__((address_space(3))) void lvoid_t;

__device__ inline void gload_lds16(const void* g, void* l) {
  __builtin_amdgcn_global_load_lds((gvoid_t*)g, (lvoid_t*)l, 16, 0, 0);
}

// ---------------- fused prep: query cvt + weight cvt + amask fragmentize ----------------
// grid 12288 x 256: [0,4096) query f32->bf16; [4096,8192) weights; [8192,12288) amask.
__global__ __launch_bounds__(256) void prep_kernel(
    const float* __restrict__ q,
    const float* __restrict__ w0, const float* __restrict__ w1,
    const float* __restrict__ w2, const float* __restrict__ w3,
    const float* __restrict__ am,
    bf16_t* __restrict__ Xq, bf16_t* __restrict__ Wbf, bf16_t* __restrict__ af) {
  const int blk = blockIdx.x;
  const int tid = threadIdx.x;
  if (blk < 4096) {
    int i = blk * 256 + tid;
    float4 v = ((const float4*)q)[i];
    union { bf16_t h[4]; uint2 u; } o;
    o.h[0] = (bf16_t)v.x; o.h[1] = (bf16_t)v.y;
    o.h[2] = (bf16_t)v.z; o.h[3] = (bf16_t)v.w;
    ((uint2*)Xq)[i] = o.u;
  } else if (blk < 8192) {
    int i = (blk - 4096) * 256 + tid;   // 0..1048575 float4
    int wsel = i >> 18;                 // 262144 float4 per weight
    int loc = i & 262143;
    const float* src = (wsel == 0) ? w0 : (wsel == 1) ? w1 : (wsel == 2) ? w2 : w3;
    float4 v = ((const float4*)src)[loc];
    union { bf16_t h[4]; uint2 u; } o;
    o.h[0] = (bf16_t)v.x; o.h[1] = (bf16_t)v.y;
    o.h[2] = (bf16_t)v.z; o.h[3] = (bf16_t)v.w;
    ((uint2*)(Wbf + (size_t)wsel * 1048576))[loc] = o.u;
  } else {
    int o = (blk - 8192) * 256 + tid;   // float4 index, 1,048,576 total
    int lane = o & 63;
    int f = o >> 6;
    int st = f & 15;
    int wslab = (f >> 4) & 7;
    int tt = f >> 7;
    int t = tt * 16 + (lane & 15);
    int s = wslab * 256 + 32 * (st >> 1) + 4 * (st & 1) + 8 * (lane >> 4);
    float4 v = *(const float4*)&am[(size_t)t * 2048 + s];
    union { bf16_t h[4]; uint2 u; } ob;
    ob.h[0] = (bf16_t)(v.x - EXPBIAS); ob.h[1] = (bf16_t)(v.y - EXPBIAS);
    ob.h[2] = (bf16_t)(v.z - EXPBIAS); ob.h[3] = (bf16_t)(v.w - EXPBIAS);
    *(uint2*)&af[(size_t)o * 4] = ob.u;
  }
}

// ---------------- NT GEMM:  C[i][j] = sum_k X[i][k] * W[j][k] + bias[j] ----------------
// 128x128 tile, BK=64, 4 waves (2x2), 16x16x32 bf16 MFMA, global_load_lds staging.
// XCD-chunked block swizzle (T1). Modes 1/2: LDS-staged epilogue -> contiguous
// 1KB/wave fragment stores.
#define CSTRIDE 134
__global__ __launch_bounds__(256) void gemm_nt(
    const bf16_t* __restrict__ Xq, const bf16_t* __restrict__ X2,
    const bf16_t* __restrict__ Wall,
    const float* __restrict__ bq, const float* __restrict__ bk,
    const float* __restrict__ bv, const float* __restrict__ bo,
    float* __restrict__ dout,
    bf16_t* __restrict__ qh, bf16_t* __restrict__ kh, bf16_t* __restrict__ vT,
    int mode_base) {
  const int mode = mode_base + blockIdx.z;
  const bf16_t* __restrict__ X = (mode < 3) ? Xq : X2;
  const bf16_t* __restrict__ W = Wall + (size_t)mode * 1048576;
  const float* __restrict__ bias = (mode == 0) ? bq : (mode == 1) ? bk : (mode == 2) ? bv : bo;

  // XCD-chunked swizzle: hw id -> logical tile (nwg = 8*32 = 256, 256%8==0)
  const int hwid = blockIdx.y * 8 + blockIdx.x;
  const int tile = (hwid & 7) * 32 + (hwid >> 3);
  const int bx = tile & 7, by = tile >> 3;

  // SM: A/B staging during K-loop (16384 bf16), C-tile [128][134] bf16 after.
  __shared__ alignas(16) bf16_t SM[128 * CSTRIDE];
  bf16_t* Alds = SM;
  bf16_t* Blds = SM + 8192;

  const int lane = threadIdx.x & 63;
  const int w = threadIdx.x >> 6;
  const int wr = w >> 1, wc = w & 1;
  const int m0 = by * 128, n0 = bx * 128;

  f32x4 acc[4][4] = {};

  for (int kk = 0; kk < 1024; kk += 64) {
    __syncthreads();
    const int rb = w * 32;
#pragma unroll
    for (int i = 0; i < 4; ++i) {
      int r = rb + i * 8 + (lane >> 3);
      int c = (lane & 7) * 8;
      gload_lds16(X + (size_t)(m0 + r) * 1024 + kk + c, &Alds[(rb + i * 8) * 64]);
      gload_lds16(W + (size_t)(n0 + r) * 1024 + kk + c, &Blds[(rb + i * 8) * 64]);
    }
    __syncthreads();
#pragma unroll
    for (int kx = 0; kx < 2; ++kx) {
      bf16x8 af[4], bfr[4];
#pragma unroll
      for (int mi = 0; mi < 4; ++mi)
        af[mi] = *(const bf16x8*)&Alds[(wr * 64 + mi * 16 + (lane & 15)) * 64 + kx * 32 + (lane >> 4) * 8];
#pragma unroll
      for (int ni = 0; ni < 4; ++ni)
        bfr[ni] = *(const bf16x8*)&Blds[(wc * 64 + ni * 16 + (lane & 15)) * 64 + kx * 32 + (lane >> 4) * 8];
#pragma unroll
      for (int mi = 0; mi < 4; ++mi)
#pragma unroll
        for (int ni = 0; ni < 4; ++ni)
          acc[mi][ni] = __builtin_amdgcn_mfma_f32_16x16x32_bf16(af[mi], bfr[ni], acc[mi][ni], 0, 0, 0);
    }
  }

  if (mode == 1 || mode == 2) {
    // ---- LDS-staged epilogue: dout fp32 + C tile to LDS, then fragment stores ----
    __syncthreads();  // all waves done reading Alds/Blds
#pragma unroll
    for (int mi = 0; mi < 4; ++mi) {
#pragma unroll
      for (int ni = 0; ni < 4; ++ni) {
#pragma unroll
        for (int r = 0; r < 4; ++r) {
          int il = wr * 64 + mi * 16 + (lane >> 4) * 4 + r;
          int jl = wc * 64 + ni * 16 + (lane & 15);
          float v = acc[mi][ni][r] + bias[n0 + jl];
          dout[(mode == 1 ? OFF_K : OFF_V) + (size_t)(m0 + il) * 1024 + n0 + jl] = v;
          SM[il * CSTRIDE + jl] = (bf16_t)v;
        }
      }
    }
    __syncthreads();
    const int s0 = m0 >> 1;       // block s base (64 s-rows)
    const int b_ = w >> 1;        // wave's batch bit
    const int hl = w & 1;         // wave's h-local
    const int bh = b_ * 16 + (n0 >> 6) + hl;
    if (mode == 1) {
      bf16_t* dst = kh + (size_t)bh * 131072;
#pragma unroll
      for (int f = 0; f < 8; ++f) {
        int sbl = f >> 2, par = (f >> 1) & 1, dh = f & 1;
        int il = 2 * (sbl * 32 + ((lane >> 2) & 3) * 8 + par * 4 + (lane & 3)) + b_;
        int jl = hl * 64 + dh * 32 + (lane >> 4) * 8;
        bf16x8 fr = *(const bf16x8*)&SM[il * CSTRIDE + jl];
        int fi = ((s0 >> 5) + sbl) * 4 + par * 2 + dh;
        *(bf16x8*)&dst[(size_t)fi * 512 + lane * 8] = fr;
      }
    } else {
      bf16_t* dst = vT + (size_t)bh * 131072;
#pragma unroll
      for (int f = 0; f < 8; ++f) {
        int sbl = f >> 2, dq = f & 3;
        int jl = hl * 64 + dq * 16 + (lane & 15);
        int il0 = 2 * (sbl * 32 + (lane >> 4) * 8) + b_;
        bf16x8 fr;
#pragma unroll
        for (int e = 0; e < 8; ++e) fr[e] = SM[(il0 + 2 * e) * CSTRIDE + jl];
        int fi = ((s0 >> 5) + sbl) * 4 + dq;
        *(bf16x8*)&dst[(size_t)fi * 512 + lane * 8] = fr;
      }
    }
  } else {
    // ---- direct epilogue (modes 0 and 3) ----
#pragma unroll
    for (int mi = 0; mi < 4; ++mi) {
#pragma unroll
      for (int ni = 0; ni < 4; ++ni) {
#pragma unroll
        for (int r = 0; r < 4; ++r) {
          int i = m0 + wr * 64 + mi * 16 + (lane >> 4) * 4 + r;
          int j = n0 + wc * 64 + ni * 16 + (lane & 15);
          float v = acc[mi][ni][r] + bias[j];
          int t = i >> 1, b = i & 1, h = j >> 6, d = j & 63;
          int bh = b * 16 + h;
          if (mode == 0) {
            qh[(size_t)bh * 131072 + t * 64 + d] = (bf16_t)(v * SCALING);
          } else {
            dout[OFF_OUT + (size_t)i * 1024 + j] = v;
          }
        }
      }
    }
  }
}

// ---------------- fused attention (R9 config + bf16 amask) ----------------
#define ALOAD(n, K0, K1, MV, KU)                                                   \
  {                                                                                \
    const int fi_ = (w * 8 + ((n) >> 1)) * 4 + ((n) & 1) * 2;                      \
    K0 = *(const bf16x8*)&kfrag[(size_t)fi_ * 512 + lane * 8];                     \
    K1 = *(const bf16x8*)&kfrag[(size_t)(fi_ + 1) * 512 + lane * 8];               \
    MV = *(const bf16x4*)&afrag[(n) * 256 + lane * 4];                             \
    KU = *(const uint32_t*)&kpm[b * 2048 + s0w + 32 * ((n) >> 1) + 4 * ((n) & 1) + 8 * g]; \
  }

__global__ __launch_bounds__(512, 4) void attn_kernel(
    const bf16_t* __restrict__ qh, const bf16_t* __restrict__ kh,
    const bf16_t* __restrict__ vT,
    const bf16_t* __restrict__ amaskF, const uint8_t* __restrict__ kpm,
    float* __restrict__ wout, bf16_t* __restrict__ X2) {
  const int lane = threadIdx.x & 63;
  const int w = threadIdx.x >> 6;   // 0..7
  const int lt = lane & 15;         // t within tile (fixed per lane)
  const int g = lane >> 4;          // 0..3
  const int bh = blockIdx.x;        // bh-major dispatch
  const int tt = blockIdx.y;
  const int t0 = tt * 16;
  const int b = bh >> 4;

  __shared__ float wsum[16][8];
  __shared__ float pbuf[8][16][68];   // +4 pad breaks bank aliasing
  __shared__ float sbuf[8][16][33];   // per-wave weight transpose chunk (16t x 32s)

  const bf16_t* __restrict__ qbase = qh + (size_t)bh * 131072;
  const bf16_t* __restrict__ kfrag = kh + (size_t)bh * 131072;
  const bf16_t* __restrict__ vfrag = vT + (size_t)bh * 131072;
  const bf16_t* __restrict__ afrag = amaskF + ((size_t)(tt * 8 + w) * 16) * 256;
  float* __restrict__ wrow = wout + (size_t)bh * 4194304;
  const int s0w = w * 256;

  // Q as B-operand: lane&15 = t, k = g*8 + j
  bf16x8 aq[2];
#pragma unroll
  for (int kx = 0; kx < 2; ++kx)
    aq[kx] = *(const bf16x8*)&qbase[(t0 + lt) * 64 + kx * 32 + g * 8];

  // ---- scores -> exp -> bf16 P fragments + row sum (depth-2 pipeline) ----
  bf16x8 pa[8];
  float ssum = 0.f;

  bf16x8 ka0, ka1, kb0, kb1, kc0, kc1;
  bf16x4 ma, mb, mc;
  uint32_t ua, ub, uc;
  ALOAD(0, ka0, ka1, ma, ua);
  ALOAD(1, kb0, kb1, mb, ub);
#pragma unroll
  for (int st = 0; st < 16; ++st) {
    if (st < 14) {
      ALOAD(st + 2, kc0, kc1, mc, uc);
    }
    f32x4 acc = {0.f, 0.f, 0.f, 0.f};
    acc = __builtin_amdgcn_mfma_f32_16x16x32_bf16(ka0, aq[0], acc, 0, 0, 0);
    acc = __builtin_amdgcn_mfma_f32_16x16x32_bf16(ka1, aq[1], acc, 0, 0, 0);
#pragma unroll
    for (int r = 0; r < 4; ++r) {
      float m = (float)ma[r];   // mask - EXPBIAS, bf16
      float val = acc[r] + m;
      val = ((ua >> (8 * r)) & 0xff) ? -__builtin_inff() : val;
      float e = __expf(val);
      ssum += e;
      pa[st >> 1][4 * (st & 1) + r] = (bf16_t)e;
    }
    ka0 = kb0; ka1 = kb1; ma = mb; ua = ub;
    kb0 = kc0; kb1 = kc1; mb = mc; ub = uc;
  }

  // ---- row sum reduce (t fixed per lane) ----
  ssum += __shfl_xor(ssum, 16, 64);
  ssum += __shfl_xor(ssum, 32, 64);
  if (lane < 16) wsum[lane][w] = ssum;
  __syncthreads();
  float ss = 0.f;
#pragma unroll
  for (int ww = 0; ww < 8; ++ww) ss += wsum[lt][ww];
  const float rl = 1.0f / ss;

  // ---- PV + interleaved transposed weight stores ----
  f32x4 po[4] = {};
  bf16x8 vfa[4], vfb[4];
#pragma unroll
  for (int dt = 0; dt < 4; ++dt)
    vfa[dt] = *(const bf16x8*)&vfrag[(size_t)((w * 8) * 4 + dt) * 512 + lane * 8];
#pragma unroll
  for (int kx = 0; kx < 8; ++kx) {
    if (kx < 7) {
#pragma unroll
      for (int dt = 0; dt < 4; ++dt)
        vfb[dt] = *(const bf16x8*)&vfrag[(size_t)((w * 8 + kx + 1) * 4 + dt) * 512 + lane * 8];
    }
    // stage this kx's normalized weights into per-wave LDS (s-local = 8g+j)
    f32x4 wv0, wv1;
#pragma unroll
    for (int r = 0; r < 4; ++r) { wv0[r] = (float)pa[kx][r] * rl; wv1[r] = (float)pa[kx][4 + r] * rl; }
    *(f32x4*)&sbuf[w][lt][8 * g] = wv0;
    *(f32x4*)&sbuf[w][lt][8 * g + 4] = wv1;
    __builtin_amdgcn_s_setprio(1);
#pragma unroll
    for (int dt = 0; dt < 4; ++dt)
      po[dt] = __builtin_amdgcn_mfma_f32_16x16x32_bf16(vfa[dt], pa[kx], po[dt], 0, 0, 0);
    __builtin_amdgcn_s_setprio(0);
    asm volatile("s_waitcnt lgkmcnt(0)" ::: "memory");
    // read back row-major and store: 8 rows x 128B contiguous per instr
#pragma unroll
    for (int p = 0; p < 2; ++p) {
      int row = 8 * p + (lane >> 3);
      int c4 = (lane & 7) * 4;
      f32x4 rv = *(const f32x4*)&sbuf[w][row][c4];
      __builtin_nontemporal_store(rv,
          (f32x4*)&wrow[(size_t)(t0 + row) * 2048 + s0w + 32 * kx + c4]);
    }
#pragma unroll
    for (int dt = 0; dt < 4; ++dt) vfa[dt] = vfb[dt];
  }
#pragma unroll
  for (int dt = 0; dt < 4; ++dt) po[dt] *= rl;

  // ---- cross-wave reduce of PV partials (O^T layout: row=d, col=t) ----
#pragma unroll
  for (int dt = 0; dt < 4; ++dt) {
    f32x4 v = po[dt];
    *(f32x4*)&pbuf[w][lt][dt * 16 + 4 * g] = v;
  }
  __syncthreads();
  int e0 = threadIdx.x * 2;
  int row = e0 >> 6, d = e0 & 63;
  float v0 = 0.f, v1 = 0.f;
#pragma unroll
  for (int ww = 0; ww < 8; ++ww) {
    v0 += pbuf[ww][row][d];
    v1 += pbuf[ww][row][d + 1];
  }
  int h = bh & 15;
  union { bf16_t hh[2]; uint32_t u; } pk;
  pk.hh[0] = (bf16_t)v0; pk.hh[1] = (bf16_t)v1;
  *(uint32_t*)&X2[(size_t)((t0 + row) * 2 + b) * 1024 + h * 64 + d] = pk.u;
}

// ---------------- launch ----------------
extern "C" void kernel_launch(void* const* d_in, const int* in_sizes, int n_in,
                              void* d_out, int out_size, void* d_ws, size_t ws_size,
                              hipStream_t stream) {
  (void)in_sizes; (void)n_in; (void)out_size; (void)ws_size;
  const float* query = (const float*)d_in[0];
  const uint8_t* kpm = (const uint8_t*)d_in[1];
  const float* amask = (const float*)d_in[2];
  const float* Wq = (const float*)d_in[3];
  const float* bq = (const float*)d_in[4];
  const float* Wk = (const float*)d_in[5];
  const float* bk = (const float*)d_in[6];
  const float* Wv = (const float*)d_in[7];
  const float* bv = (const float*)d_in[8];
  const float* Wo = (const float*)d_in[9];
  const float* bo = (const float*)d_in[10];
  float* dout = (float*)d_out;
  char* ws = (char*)d_ws;

  bf16_t* Xq = (bf16_t*)(ws + WS_XQ);
  bf16_t* Wbf = (bf16_t*)(ws + WS_W);
  bf16_t* qh = (bf16_t*)(ws + WS_QH);
  bf16_t* kh = (bf16_t*)(ws + WS_KH);
  bf16_t* vT = (bf16_t*)(ws + WS_VT);
  bf16_t* X2 = (bf16_t*)(ws + WS_X2);
  bf16_t* amF = (bf16_t*)(ws + WS_AM);

  prep_kernel<<<12288, 256, 0, stream>>>(query, Wq, Wk, Wv, Wo, amask, Xq, Wbf, amF);
  gemm_nt<<<dim3(8, 32, 3), 256, 0, stream>>>(Xq, X2, Wbf, bq, bk, bv, bo, dout, qh, kh, vT, 0);
  attn_kernel<<<dim3(32, 128), 512, 0, stream>>>(qh, kh, vT, amF, kpm, dout + OFF_WEI, X2);
  gemm_nt<<<dim3(8, 32, 1), 256, 0, stream>>>(Xq, X2, Wbf, bq, bk, bv, bo, dout, qh, kh, vT, 3);
}

// Round 17
// 242.425 us; speedup vs baseline: 1.0530x; 1.0530x over previous
//
#include <hip/hip_runtime.h>
#include <hip/hip_bf16.h>
#include <stdint.h>

typedef __bf16 bf16_t;
typedef __bf16 bf16x8 __attribute__((ext_vector_type(8)));
typedef float f32x4 __attribute__((ext_vector_type(4)));

#define SCALING 0.125f
#define EXPBIAS 20.0f

// ws layout (byte offsets)
#define WS_XQ  (0u)         // [4096][1024] bf16 query
#define WS_W   (8u << 20)   // 4 x [1024][1024] bf16 (Wq,Wk,Wv,Wo)
#define WS_QH  (16u << 20)  // [32][2048][64] bf16  q*scale, head layout
#define WS_KH  (24u << 20)  // [32] fragment-major K (2048*64 bf16 per bh)
#define WS_VT  (32u << 20)  // [32] fragment-major V (2048*64 bf16 per bh)
#define WS_X2  (40u << 20)  // [4096][1024] bf16  attention head outputs
#define WS_AM  (48u << 20)  // 16.8 MB fragment-major amask (f32, minus EXPBIAS)

// d_out offsets (float elements)
#define OFF_OUT 0
#define OFF_WEI 4194304
#define OFF_K   138412032
#define OFF_V   142606336

typedef const __attribute__((address_space(1))) void gvoid_t;
typedef __attribute__((address_space(3))) void lvoid_t;

__device__ inline void gload_lds16(const void* g, void* l) {
  __builtin_amdgcn_global_load_lds((gvoid_t*)g, (lvoid_t*)l, 16, 0, 0);
}

// ---------------- fused prep: query cvt + weight cvt + amask fragmentize ----------------
// grid 12288 x 256: [0,4096) query f32->bf16; [4096,8192) weights; [8192,12288) amask.
__global__ __launch_bounds__(256) void prep_kernel(
    const float* __restrict__ q,
    const float* __restrict__ w0, const float* __restrict__ w1,
    const float* __restrict__ w2, const float* __restrict__ w3,
    const float* __restrict__ am,
    bf16_t* __restrict__ Xq, bf16_t* __restrict__ Wbf, float* __restrict__ af) {
  const int blk = blockIdx.x;
  const int tid = threadIdx.x;
  if (blk < 4096) {
    int i = blk * 256 + tid;
    float4 v = ((const float4*)q)[i];
    union { bf16_t h[4]; uint2 u; } o;
    o.h[0] = (bf16_t)v.x; o.h[1] = (bf16_t)v.y;
    o.h[2] = (bf16_t)v.z; o.h[3] = (bf16_t)v.w;
    ((uint2*)Xq)[i] = o.u;
  } else if (blk < 8192) {
    int i = (blk - 4096) * 256 + tid;   // 0..1048575 float4
    int wsel = i >> 18;                 // 262144 float4 per weight
    int loc = i & 262143;
    const float* src = (wsel == 0) ? w0 : (wsel == 1) ? w1 : (wsel == 2) ? w2 : w3;
    float4 v = ((const float4*)src)[loc];
    union { bf16_t h[4]; uint2 u; } o;
    o.h[0] = (bf16_t)v.x; o.h[1] = (bf16_t)v.y;
    o.h[2] = (bf16_t)v.z; o.h[3] = (bf16_t)v.w;
    ((uint2*)(Wbf + (size_t)wsel * 1048576))[loc] = o.u;
  } else {
    int o = (blk - 8192) * 256 + tid;   // float4 index, 1,048,576 total
    int lane = o & 63;
    int f = o >> 6;
    int st = f & 15;
    int wslab = (f >> 4) & 7;
    int tt = f >> 7;
    int t = tt * 16 + (lane & 15);
    int s = wslab * 256 + 32 * (st >> 1) + 4 * (st & 1) + 8 * (lane >> 4);
    float4 v = *(const float4*)&am[(size_t)t * 2048 + s];
    v.x -= EXPBIAS; v.y -= EXPBIAS; v.z -= EXPBIAS; v.w -= EXPBIAS;
    *(float4*)&af[(size_t)o * 4] = v;
  }
}

// ---------------- NT GEMM:  C[i][j] = sum_k X[i][k] * W[j][k] + bias[j] ----------------
// 128x128 tile, BK=64, 4 waves (2x2), 16x16x32 bf16 MFMA, global_load_lds staging.
// XCD-chunked block swizzle (T1): each XCD owns 32 contiguous tiles ->
// 4 A-panels + 8 B-panels (~3MB) stay L2-resident per XCD.
// Modes 1/2: LDS-staged epilogue -> kh/vT fragment stores become contiguous
// 1KB/wave global_store_dwordx4.
#define CSTRIDE 134
__global__ __launch_bounds__(256) void gemm_nt(
    const bf16_t* __restrict__ Xq, const bf16_t* __restrict__ X2,
    const bf16_t* __restrict__ Wall,
    const float* __restrict__ bq, const float* __restrict__ bk,
    const float* __restrict__ bv, const float* __restrict__ bo,
    float* __restrict__ dout,
    bf16_t* __restrict__ qh, bf16_t* __restrict__ kh, bf16_t* __restrict__ vT,
    int mode_base) {
  const int mode = mode_base + blockIdx.z;
  const bf16_t* __restrict__ X = (mode < 3) ? Xq : X2;
  const bf16_t* __restrict__ W = Wall + (size_t)mode * 1048576;
  const float* __restrict__ bias = (mode == 0) ? bq : (mode == 1) ? bk : (mode == 2) ? bv : bo;

  // XCD-chunked swizzle: hw id -> logical tile (nwg = 8*32 = 256, 256%8==0)
  const int hwid = blockIdx.y * 8 + blockIdx.x;
  const int tile = (hwid & 7) * 32 + (hwid >> 3);
  const int bx = tile & 7, by = tile >> 3;

  // SM: A/B staging during K-loop (16384 bf16), C-tile [128][134] bf16 after.
  __shared__ alignas(16) bf16_t SM[128 * CSTRIDE];
  bf16_t* Alds = SM;
  bf16_t* Blds = SM + 8192;

  const int lane = threadIdx.x & 63;
  const int w = threadIdx.x >> 6;
  const int wr = w >> 1, wc = w & 1;
  const int m0 = by * 128, n0 = bx * 128;

  f32x4 acc[4][4] = {};

  for (int kk = 0; kk < 1024; kk += 64) {
    __syncthreads();
    const int rb = w * 32;
#pragma unroll
    for (int i = 0; i < 4; ++i) {
      int r = rb + i * 8 + (lane >> 3);
      int c = (lane & 7) * 8;
      gload_lds16(X + (size_t)(m0 + r) * 1024 + kk + c, &Alds[(rb + i * 8) * 64]);
      gload_lds16(W + (size_t)(n0 + r) * 1024 + kk + c, &Blds[(rb + i * 8) * 64]);
    }
    __syncthreads();
#pragma unroll
    for (int kx = 0; kx < 2; ++kx) {
      bf16x8 af[4], bfr[4];
#pragma unroll
      for (int mi = 0; mi < 4; ++mi)
        af[mi] = *(const bf16x8*)&Alds[(wr * 64 + mi * 16 + (lane & 15)) * 64 + kx * 32 + (lane >> 4) * 8];
#pragma unroll
      for (int ni = 0; ni < 4; ++ni)
        bfr[ni] = *(const bf16x8*)&Blds[(wc * 64 + ni * 16 + (lane & 15)) * 64 + kx * 32 + (lane >> 4) * 8];
#pragma unroll
      for (int mi = 0; mi < 4; ++mi)
#pragma unroll
        for (int ni = 0; ni < 4; ++ni)
          acc[mi][ni] = __builtin_amdgcn_mfma_f32_16x16x32_bf16(af[mi], bfr[ni], acc[mi][ni], 0, 0, 0);
    }
  }

  if (mode == 1 || mode == 2) {
    // ---- LDS-staged epilogue: dout fp32 + C tile to LDS, then fragment stores ----
    __syncthreads();  // all waves done reading Alds/Blds
#pragma unroll
    for (int mi = 0; mi < 4; ++mi) {
#pragma unroll
      for (int ni = 0; ni < 4; ++ni) {
#pragma unroll
        for (int r = 0; r < 4; ++r) {
          int il = wr * 64 + mi * 16 + (lane >> 4) * 4 + r;
          int jl = wc * 64 + ni * 16 + (lane & 15);
          float v = acc[mi][ni][r] + bias[n0 + jl];
          dout[(mode == 1 ? OFF_K : OFF_V) + (size_t)(m0 + il) * 1024 + n0 + jl] = v;
          SM[il * CSTRIDE + jl] = (bf16_t)v;
        }
      }
    }
    __syncthreads();
    const int s0 = m0 >> 1;       // block s base (64 s-rows)
    const int b_ = w >> 1;        // wave's batch bit
    const int hl = w & 1;         // wave's h-local
    const int bh = b_ * 16 + (n0 >> 6) + hl;
    if (mode == 1) {
      bf16_t* dst = kh + (size_t)bh * 131072;
#pragma unroll
      for (int f = 0; f < 8; ++f) {
        int sbl = f >> 2, par = (f >> 1) & 1, dh = f & 1;
        int il = 2 * (sbl * 32 + ((lane >> 2) & 3) * 8 + par * 4 + (lane & 3)) + b_;
        int jl = hl * 64 + dh * 32 + (lane >> 4) * 8;
        bf16x8 fr = *(const bf16x8*)&SM[il * CSTRIDE + jl];
        int fi = ((s0 >> 5) + sbl) * 4 + par * 2 + dh;
        *(bf16x8*)&dst[(size_t)fi * 512 + lane * 8] = fr;
      }
    } else {
      bf16_t* dst = vT + (size_t)bh * 131072;
#pragma unroll
      for (int f = 0; f < 8; ++f) {
        int sbl = f >> 2, dq = f & 3;
        int jl = hl * 64 + dq * 16 + (lane & 15);
        int il0 = 2 * (sbl * 32 + (lane >> 4) * 8) + b_;
        bf16x8 fr;
#pragma unroll
        for (int e = 0; e < 8; ++e) fr[e] = SM[(il0 + 2 * e) * CSTRIDE + jl];
        int fi = ((s0 >> 5) + sbl) * 4 + dq;
        *(bf16x8*)&dst[(size_t)fi * 512 + lane * 8] = fr;
      }
    }
  } else {
    // ---- direct epilogue (modes 0 and 3) ----
#pragma unroll
    for (int mi = 0; mi < 4; ++mi) {
#pragma unroll
      for (int ni = 0; ni < 4; ++ni) {
#pragma unroll
        for (int r = 0; r < 4; ++r) {
          int i = m0 + wr * 64 + mi * 16 + (lane >> 4) * 4 + r;
          int j = n0 + wc * 64 + ni * 16 + (lane & 15);
          float v = acc[mi][ni][r] + bias[j];
          int t = i >> 1, b = i & 1, h = j >> 6, d = j & 63;
          int bh = b * 16 + h;
          if (mode == 0) {
            qh[(size_t)bh * 131072 + t * 64 + d] = (bf16_t)(v * SCALING);
          } else {
            dout[OFF_OUT + (size_t)i * 1024 + j] = v;
          }
        }
      }
    }
  }
}

// ---------------- fused attention (R9 config: fragment-major, LDS-transposed stores) ----------------
#define ALOAD(n, K0, K1, MV, KU)                                                   \
  {                                                                                \
    const int fi_ = (w * 8 + ((n) >> 1)) * 4 + ((n) & 1) * 2;                      \
    K0 = *(const bf16x8*)&kfrag[(size_t)fi_ * 512 + lane * 8];                     \
    K1 = *(const bf16x8*)&kfrag[(size_t)(fi_ + 1) * 512 + lane * 8];               \
    MV = *(const float4*)&afrag[(n) * 256 + lane * 4];                             \
    KU = *(const uint32_t*)&kpm[b * 2048 + s0w + 32 * ((n) >> 1) + 4 * ((n) & 1) + 8 * g]; \
  }

__global__ __launch_bounds__(512, 4) void attn_kernel(
    const bf16_t* __restrict__ qh, const bf16_t* __restrict__ kh,
    const bf16_t* __restrict__ vT,
    const float* __restrict__ amaskF, const uint8_t* __restrict__ kpm,
    float* __restrict__ wout, bf16_t* __restrict__ X2) {
  const int lane = threadIdx.x & 63;
  const int w = threadIdx.x >> 6;   // 0..7
  const int lt = lane & 15;         // t within tile (fixed per lane)
  const int g = lane >> 4;          // 0..3
  const int bh = blockIdx.x;        // bh-major dispatch
  const int tt = blockIdx.y;
  const int t0 = tt * 16;
  const int b = bh >> 4;

  __shared__ float wsum[16][8];
  __shared__ float pbuf[8][16][68];   // +4 pad breaks bank aliasing
  __shared__ float sbuf[8][16][33];   // per-wave weight transpose chunk (16t x 32s)

  const bf16_t* __restrict__ qbase = qh + (size_t)bh * 131072;
  const bf16_t* __restrict__ kfrag = kh + (size_t)bh * 131072;
  const bf16_t* __restrict__ vfrag = vT + (size_t)bh * 131072;
  const float* __restrict__ afrag = amaskF + ((size_t)(tt * 8 + w) * 16) * 256;
  float* __restrict__ wrow = wout + (size_t)bh * 4194304;
  const int s0w = w * 256;

  // Q as B-operand: lane&15 = t, k = g*8 + j
  bf16x8 aq[2];
#pragma unroll
  for (int kx = 0; kx < 2; ++kx)
    aq[kx] = *(const bf16x8*)&qbase[(t0 + lt) * 64 + kx * 32 + g * 8];

  // ---- scores -> exp -> bf16 P fragments + row sum (depth-2 pipeline) ----
  bf16x8 pa[8];
  float ssum = 0.f;

  bf16x8 ka0, ka1, kb0, kb1, kc0, kc1;
  float4 ma, mb, mc;
  uint32_t ua, ub, uc;
  ALOAD(0, ka0, ka1, ma, ua);
  ALOAD(1, kb0, kb1, mb, ub);
#pragma unroll
  for (int st = 0; st < 16; ++st) {
    if (st < 14) {
      ALOAD(st + 2, kc0, kc1, mc, uc);
    }
    f32x4 acc = {0.f, 0.f, 0.f, 0.f};
    acc = __builtin_amdgcn_mfma_f32_16x16x32_bf16(ka0, aq[0], acc, 0, 0, 0);
    acc = __builtin_amdgcn_mfma_f32_16x16x32_bf16(ka1, aq[1], acc, 0, 0, 0);
#pragma unroll
    for (int r = 0; r < 4; ++r) {
      float m = (r == 0) ? ma.x : (r == 1) ? ma.y : (r == 2) ? ma.z : ma.w;
      float val = acc[r] + m;  // m already includes -EXPBIAS
      val = ((ua >> (8 * r)) & 0xff) ? -__builtin_inff() : val;
      float e = __expf(val);
      ssum += e;
      pa[st >> 1][4 * (st & 1) + r] = (bf16_t)e;
    }
    ka0 = kb0; ka1 = kb1; ma = mb; ua = ub;
    kb0 = kc0; kb1 = kc1; mb = mc; ub = uc;
  }

  // ---- row sum reduce (t fixed per lane) ----
  ssum += __shfl_xor(ssum, 16, 64);
  ssum += __shfl_xor(ssum, 32, 64);
  if (lane < 16) wsum[lane][w] = ssum;
  __syncthreads();
  float ss = 0.f;
#pragma unroll
  for (int ww = 0; ww < 8; ++ww) ss += wsum[lt][ww];
  const float rl = 1.0f / ss;

  // ---- PV + interleaved transposed weight stores ----
  f32x4 po[4] = {};
  bf16x8 vfa[4], vfb[4];
#pragma unroll
  for (int dt = 0; dt < 4; ++dt)
    vfa[dt] = *(const bf16x8*)&vfrag[(size_t)((w * 8) * 4 + dt) * 512 + lane * 8];
#pragma unroll
  for (int kx = 0; kx < 8; ++kx) {
    if (kx < 7) {
#pragma unroll
      for (int dt = 0; dt < 4; ++dt)
        vfb[dt] = *(const bf16x8*)&vfrag[(size_t)((w * 8 + kx + 1) * 4 + dt) * 512 + lane * 8];
    }
    // stage this kx's normalized weights into per-wave LDS (s-local = 8g+j)
    f32x4 wv0, wv1;
#pragma unroll
    for (int r = 0; r < 4; ++r) { wv0[r] = (float)pa[kx][r] * rl; wv1[r] = (float)pa[kx][4 + r] * rl; }
    *(f32x4*)&sbuf[w][lt][8 * g] = wv0;
    *(f32x4*)&sbuf[w][lt][8 * g + 4] = wv1;
    __builtin_amdgcn_s_setprio(1);
#pragma unroll
    for (int dt = 0; dt < 4; ++dt)
      po[dt] = __builtin_amdgcn_mfma_f32_16x16x32_bf16(vfa[dt], pa[kx], po[dt], 0, 0, 0);
    __builtin_amdgcn_s_setprio(0);
    asm volatile("s_waitcnt lgkmcnt(0)" ::: "memory");
    // read back row-major and store: 8 rows x 128B contiguous per instr
#pragma unroll
    for (int p = 0; p < 2; ++p) {
      int row = 8 * p + (lane >> 3);
      int c4 = (lane & 7) * 4;
      f32x4 rv = *(const f32x4*)&sbuf[w][row][c4];
      __builtin_nontemporal_store(rv,
          (f32x4*)&wrow[(size_t)(t0 + row) * 2048 + s0w + 32 * kx + c4]);
    }
#pragma unroll
    for (int dt = 0; dt < 4; ++dt) vfa[dt] = vfb[dt];
  }
#pragma unroll
  for (int dt = 0; dt < 4; ++dt) po[dt] *= rl;

  // ---- cross-wave reduce of PV partials (O^T layout: row=d, col=t) ----
#pragma unroll
  for (int dt = 0; dt < 4; ++dt) {
    f32x4 v = po[dt];
    *(f32x4*)&pbuf[w][lt][dt * 16 + 4 * g] = v;
  }
  __syncthreads();
  int e0 = threadIdx.x * 2;
  int row = e0 >> 6, d = e0 & 63;
  float v0 = 0.f, v1 = 0.f;
#pragma unroll
  for (int ww = 0; ww < 8; ++ww) {
    v0 += pbuf[ww][row][d];
    v1 += pbuf[ww][row][d + 1];
  }
  int h = bh & 15;
  union { bf16_t hh[2]; uint32_t u; } pk;
  pk.hh[0] = (bf16_t)v0; pk.hh[1] = (bf16_t)v1;
  *(uint32_t*)&X2[(size_t)((t0 + row) * 2 + b) * 1024 + h * 64 + d] = pk.u;
}

// ---------------- launch ----------------
extern "C" void kernel_launch(void* const* d_in, const int* in_sizes, int n_in,
                              void* d_out, int out_size, void* d_ws, size_t ws_size,
                              hipStream_t stream) {
  (void)in_sizes; (void)n_in; (void)out_size; (void)ws_size;
  const float* query = (const float*)d_in[0];
  const uint8_t* kpm = (const uint8_t*)d_in[1];
  const float* amask = (const float*)d_in[2];
  const float* Wq = (const float*)d_in[3];
  const float* bq = (const float*)d_in[4];
  const float* Wk = (const float*)d_in[5];
  const float* bk = (const float*)d_in[6];
  const float* Wv = (const float*)d_in[7];
  const float* bv = (const float*)d_in[8];
  const float* Wo = (const float*)d_in[9];
  const float* bo = (const float*)d_in[10];
  float* dout = (float*)d_out;
  char* ws = (char*)d_ws;

  bf16_t* Xq = (bf16_t*)(ws + WS_XQ);
  bf16_t* Wbf = (bf16_t*)(ws + WS_W);
  bf16_t* qh = (bf16_t*)(ws + WS_QH);
  bf16_t* kh = (bf16_t*)(ws + WS_KH);
  bf16_t* vT = (bf16_t*)(ws + WS_VT);
  bf16_t* X2 = (bf16_t*)(ws + WS_X2);
  float* amF = (float*)(ws + WS_AM);

  prep_kernel<<<12288, 256, 0, stream>>>(query, Wq, Wk, Wv, Wo, amask, Xq, Wbf, amF);
  gemm_nt<<<dim3(8, 32, 3), 256, 0, stream>>>(Xq, X2, Wbf, bq, bk, bv, bo, dout, qh, kh, vT, 0);
  attn_kernel<<<dim3(32, 128), 512, 0, stream>>>(qh, kh, vT, amF, kpm, dout + OFF_WEI, X2);
  gemm_nt<<<dim3(8, 32, 1), 256, 0, stream>>>(Xq, X2, Wbf, bq, bk, bv, bo, dout, qh, kh, vT, 3);
}

// Round 18
// 240.309 us; speedup vs baseline: 1.0623x; 1.0088x over previous
//
#include <hip/hip_runtime.h>
#include <hip/hip_bf16.h>
#include <stdint.h>

typedef __bf16 bf16_t;
typedef __bf16 bf16x8 __attribute__((ext_vector_type(8)));
typedef float f32x4 __attribute__((ext_vector_type(4)));

#define SCALING 0.125f
#define EXPBIAS 20.0f

// ws layout (byte offsets)
#define WS_XQ  (0u)         // [4096][1024] bf16 query
#define WS_W   (8u << 20)   // 4 x [1024][1024] bf16 (Wq,Wk,Wv,Wo)
#define WS_QH  (16u << 20)  // [32][2048][64] bf16  q*scale, head layout
#define WS_KH  (24u << 20)  // [32] fragment-major K (2048*64 bf16 per bh)
#define WS_VT  (32u << 20)  // [32] fragment-major V (2048*64 bf16 per bh)
#define WS_X2  (40u << 20)  // [4096][1024] bf16  attention head outputs
#define WS_AM  (48u << 20)  // 16.8 MB fragment-major amask (f32, minus EXPBIAS)

// d_out offsets (float elements)
#define OFF_OUT 0
#define OFF_WEI 4194304
#define OFF_K   138412032
#define OFF_V   142606336

typedef const __attribute__((address_space(1))) void gvoid_t;
typedef __attribute__((address_space(3))) void lvoid_t;

__device__ inline void gload_lds16(const void* g, void* l) {
  __builtin_amdgcn_global_load_lds((gvoid_t*)g, (lvoid_t*)l, 16, 0, 0);
}

// ---------------- fused prep: query cvt + weight cvt + amask fragmentize ----------------
// grid 12288 x 256: [0,4096) query f32->bf16; [4096,8192) weights; [8192,12288) amask.
__global__ __launch_bounds__(256) void prep_kernel(
    const float* __restrict__ q,
    const float* __restrict__ w0, const float* __restrict__ w1,
    const float* __restrict__ w2, const float* __restrict__ w3,
    const float* __restrict__ am,
    bf16_t* __restrict__ Xq, bf16_t* __restrict__ Wbf, float* __restrict__ af) {
  const int blk = blockIdx.x;
  const int tid = threadIdx.x;
  if (blk < 4096) {
    int i = blk * 256 + tid;
    float4 v = ((const float4*)q)[i];
    union { bf16_t h[4]; uint2 u; } o;
    o.h[0] = (bf16_t)v.x; o.h[1] = (bf16_t)v.y;
    o.h[2] = (bf16_t)v.z; o.h[3] = (bf16_t)v.w;
    ((uint2*)Xq)[i] = o.u;
  } else if (blk < 8192) {
    int i = (blk - 4096) * 256 + tid;   // 0..1048575 float4
    int wsel = i >> 18;                 // 262144 float4 per weight
    int loc = i & 262143;
    const float* src = (wsel == 0) ? w0 : (wsel == 1) ? w1 : (wsel == 2) ? w2 : w3;
    float4 v = ((const float4*)src)[loc];
    union { bf16_t h[4]; uint2 u; } o;
    o.h[0] = (bf16_t)v.x; o.h[1] = (bf16_t)v.y;
    o.h[2] = (bf16_t)v.z; o.h[3] = (bf16_t)v.w;
    ((uint2*)(Wbf + (size_t)wsel * 1048576))[loc] = o.u;
  } else {
    int o = (blk - 8192) * 256 + tid;   // float4 index, 1,048,576 total
    int lane = o & 63;
    int f = o >> 6;
    int st = f & 15;
    int wslab = (f >> 4) & 7;
    int tt = f >> 7;
    int t = tt * 16 + (lane & 15);
    int s = wslab * 256 + 32 * (st >> 1) + 4 * (st & 1) + 8 * (lane >> 4);
    float4 v = *(const float4*)&am[(size_t)t * 2048 + s];
    v.x -= EXPBIAS; v.y -= EXPBIAS; v.z -= EXPBIAS; v.w -= EXPBIAS;
    *(float4*)&af[(size_t)o * 4] = v;
  }
}

// ---------------- NT GEMM:  C[i][j] = sum_k X[i][k] * W[j][k] + bias[j] ----------------
// 128x128 tile, BK=32 DOUBLE-BUFFERED (T3-minimum 2-phase): stage tile t+1
// is issued before tile t's ds_read+MFMA, one vmcnt-drain+barrier per tile.
// 4 buffers x 8KB = 32KB inside the 34.3KB epilogue allocation -> occupancy
// unchanged (4 blocks/CU). XCD-chunked block swizzle (T1). Modes 1/2:
// LDS-staged epilogue -> contiguous 1KB/wave fragment stores.
#define CSTRIDE 134
__global__ __launch_bounds__(256) void gemm_nt(
    const bf16_t* __restrict__ Xq, const bf16_t* __restrict__ X2,
    const bf16_t* __restrict__ Wall,
    const float* __restrict__ bq, const float* __restrict__ bk,
    const float* __restrict__ bv, const float* __restrict__ bo,
    float* __restrict__ dout,
    bf16_t* __restrict__ qh, bf16_t* __restrict__ kh, bf16_t* __restrict__ vT,
    int mode_base) {
  const int mode = mode_base + blockIdx.z;
  const bf16_t* __restrict__ X = (mode < 3) ? Xq : X2;
  const bf16_t* __restrict__ W = Wall + (size_t)mode * 1048576;
  const float* __restrict__ bias = (mode == 0) ? bq : (mode == 1) ? bk : (mode == 2) ? bv : bo;

  // XCD-chunked swizzle: hw id -> logical tile (nwg = 8*32 = 256, 256%8==0)
  const int hwid = blockIdx.y * 8 + blockIdx.x;
  const int tile = (hwid & 7) * 32 + (hwid >> 3);
  const int bx = tile & 7, by = tile >> 3;

  // SM: A0/A1/B0/B1 staging (4 x 4096 bf16) during K-loop; C-tile after.
  __shared__ alignas(16) bf16_t SM[128 * CSTRIDE];

  const int lane = threadIdx.x & 63;
  const int w = threadIdx.x >> 6;
  const int wr = w >> 1, wc = w & 1;
  const int m0 = by * 128, n0 = bx * 128;

  // Stage tile (kk = t*32) into buffer half: [128][32] row-major, linear.
  // Wave-uniform LDS base (p*4+w)*512 elems; lane covers row w*16+(l>>2)+p*64,
  // col (l&3)*8 -> LDS offset = base + lane*16B (linear, verified).
  const int srow = (lane >> 2);
  const int scol = (lane & 3) * 8;

  f32x4 acc[4][4] = {};

  // prologue: stage tile 0 into half 0
#pragma unroll
  for (int p = 0; p < 2; ++p) {
    gload_lds16(X + (size_t)(m0 + p * 64 + w * 16 + srow) * 1024 + 0 + scol,
                &SM[0 + (p * 4 + w) * 512]);
    gload_lds16(W + (size_t)(n0 + p * 64 + w * 16 + srow) * 1024 + 0 + scol,
                &SM[8192 + (p * 4 + w) * 512]);
  }
  __syncthreads();   // compiler inserts vmcnt(0) drain before barrier

  int cur = 0;
  for (int t = 0; t < 32; ++t) {
    if (t < 31) {
      const int kk = (t + 1) * 32;
      const int nxt = cur ^ 1;
#pragma unroll
      for (int p = 0; p < 2; ++p) {
        gload_lds16(X + (size_t)(m0 + p * 64 + w * 16 + srow) * 1024 + kk + scol,
                    &SM[nxt * 4096 + (p * 4 + w) * 512]);
        gload_lds16(W + (size_t)(n0 + p * 64 + w * 16 + srow) * 1024 + kk + scol,
                    &SM[8192 + nxt * 4096 + (p * 4 + w) * 512]);
      }
    }
    const bf16_t* Ab = &SM[cur * 4096];
    const bf16_t* Bb = &SM[8192 + cur * 4096];
    bf16x8 af[4], bfr[4];
#pragma unroll
    for (int mi = 0; mi < 4; ++mi)
      af[mi] = *(const bf16x8*)&Ab[(wr * 64 + mi * 16 + (lane & 15)) * 32 + (lane >> 4) * 8];
#pragma unroll
    for (int ni = 0; ni < 4; ++ni)
      bfr[ni] = *(const bf16x8*)&Bb[(wc * 64 + ni * 16 + (lane & 15)) * 32 + (lane >> 4) * 8];
#pragma unroll
    for (int mi = 0; mi < 4; ++mi)
#pragma unroll
      for (int ni = 0; ni < 4; ++ni)
        acc[mi][ni] = __builtin_amdgcn_mfma_f32_16x16x32_bf16(af[mi], bfr[ni], acc[mi][ni], 0, 0, 0);
    __syncthreads();   // drain of this iter's stage happened during MFMA
    cur ^= 1;
  }

  if (mode == 1 || mode == 2) {
    // ---- LDS-staged epilogue: dout fp32 + C tile to LDS, then fragment stores ----
#pragma unroll
    for (int mi = 0; mi < 4; ++mi) {
#pragma unroll
      for (int ni = 0; ni < 4; ++ni) {
#pragma unroll
        for (int r = 0; r < 4; ++r) {
          int il = wr * 64 + mi * 16 + (lane >> 4) * 4 + r;
          int jl = wc * 64 + ni * 16 + (lane & 15);
          float v = acc[mi][ni][r] + bias[n0 + jl];
          dout[(mode == 1 ? OFF_K : OFF_V) + (size_t)(m0 + il) * 1024 + n0 + jl] = v;
          SM[il * CSTRIDE + jl] = (bf16_t)v;
        }
      }
    }
    __syncthreads();
    const int s0 = m0 >> 1;       // block s base (64 s-rows)
    const int b_ = w >> 1;        // wave's batch bit
    const int hl = w & 1;         // wave's h-local
    const int bh = b_ * 16 + (n0 >> 6) + hl;
    if (mode == 1) {
      bf16_t* dst = kh + (size_t)bh * 131072;
#pragma unroll
      for (int f = 0; f < 8; ++f) {
        int sbl = f >> 2, par = (f >> 1) & 1, dh = f & 1;
        int il = 2 * (sbl * 32 + ((lane >> 2) & 3) * 8 + par * 4 + (lane & 3)) + b_;
        int jl = hl * 64 + dh * 32 + (lane >> 4) * 8;
        bf16x8 fr = *(const bf16x8*)&SM[il * CSTRIDE + jl];
        int fi = ((s0 >> 5) + sbl) * 4 + par * 2 + dh;
        *(bf16x8*)&dst[(size_t)fi * 512 + lane * 8] = fr;
      }
    } else {
      bf16_t* dst = vT + (size_t)bh * 131072;
#pragma unroll
      for (int f = 0; f < 8; ++f) {
        int sbl = f >> 2, dq = f & 3;
        int jl = hl * 64 + dq * 16 + (lane & 15);
        int il0 = 2 * (sbl * 32 + (lane >> 4) * 8) + b_;
        bf16x8 fr;
#pragma unroll
        for (int e = 0; e < 8; ++e) fr[e] = SM[(il0 + 2 * e) * CSTRIDE + jl];
        int fi = ((s0 >> 5) + sbl) * 4 + dq;
        *(bf16x8*)&dst[(size_t)fi * 512 + lane * 8] = fr;
      }
    }
  } else {
    // ---- direct epilogue (modes 0 and 3) ----
#pragma unroll
    for (int mi = 0; mi < 4; ++mi) {
#pragma unroll
      for (int ni = 0; ni < 4; ++ni) {
#pragma unroll
        for (int r = 0; r < 4; ++r) {
          int i = m0 + wr * 64 + mi * 16 + (lane >> 4) * 4 + r;
          int j = n0 + wc * 64 + ni * 16 + (lane & 15);
          float v = acc[mi][ni][r] + bias[j];
          int t = i >> 1, b = i & 1, h = j >> 6, d = j & 63;
          int bh = b * 16 + h;
          if (mode == 0) {
            qh[(size_t)bh * 131072 + t * 64 + d] = (bf16_t)(v * SCALING);
          } else {
            dout[OFF_OUT + (size_t)i * 1024 + j] = v;
          }
        }
      }
    }
  }
}

// ---------------- fused attention (R9 config: fragment-major, LDS-transposed stores) ----------------
#define ALOAD(n, K0, K1, MV, KU)                                                   \
  {                                                                                \
    const int fi_ = (w * 8 + ((n) >> 1)) * 4 + ((n) & 1) * 2;                      \
    K0 = *(const bf16x8*)&kfrag[(size_t)fi_ * 512 + lane * 8];                     \
    K1 = *(const bf16x8*)&kfrag[(size_t)(fi_ + 1) * 512 + lane * 8];               \
    MV = *(const float4*)&afrag[(n) * 256 + lane * 4];                             \
    KU = *(const uint32_t*)&kpm[b * 2048 + s0w + 32 * ((n) >> 1) + 4 * ((n) & 1) + 8 * g]; \
  }

__global__ __launch_bounds__(512, 4) void attn_kernel(
    const bf16_t* __restrict__ qh, const bf16_t* __restrict__ kh,
    const bf16_t* __restrict__ vT,
    const float* __restrict__ amaskF, const uint8_t* __restrict__ kpm,
    float* __restrict__ wout, bf16_t* __restrict__ X2) {
  const int lane = threadIdx.x & 63;
  const int w = threadIdx.x >> 6;   // 0..7
  const int lt = lane & 15;         // t within tile (fixed per lane)
  const int g = lane >> 4;          // 0..3
  const int bh = blockIdx.x;        // bh-major dispatch
  const int tt = blockIdx.y;
  const int t0 = tt * 16;
  const int b = bh >> 4;

  __shared__ float wsum[16][8];
  __shared__ float pbuf[8][16][68];   // +4 pad breaks bank aliasing
  __shared__ float sbuf[8][16][33];   // per-wave weight transpose chunk (16t x 32s)

  const bf16_t* __restrict__ qbase = qh + (size_t)bh * 131072;
  const bf16_t* __restrict__ kfrag = kh + (size_t)bh * 131072;
  const bf16_t* __restrict__ vfrag = vT + (size_t)bh * 131072;
  const float* __restrict__ afrag = amaskF + ((size_t)(tt * 8 + w) * 16) * 256;
  float* __restrict__ wrow = wout + (size_t)bh * 4194304;
  const int s0w = w * 256;

  // Q as B-operand: lane&15 = t, k = g*8 + j
  bf16x8 aq[2];
#pragma unroll
  for (int kx = 0; kx < 2; ++kx)
    aq[kx] = *(const bf16x8*)&qbase[(t0 + lt) * 64 + kx * 32 + g * 8];

  // ---- scores -> exp -> bf16 P fragments + row sum (depth-2 pipeline) ----
  bf16x8 pa[8];
  float ssum = 0.f;

  bf16x8 ka0, ka1, kb0, kb1, kc0, kc1;
  float4 ma, mb, mc;
  uint32_t ua, ub, uc;
  ALOAD(0, ka0, ka1, ma, ua);
  ALOAD(1, kb0, kb1, mb, ub);
#pragma unroll
  for (int st = 0; st < 16; ++st) {
    if (st < 14) {
      ALOAD(st + 2, kc0, kc1, mc, uc);
    }
    f32x4 acc = {0.f, 0.f, 0.f, 0.f};
    acc = __builtin_amdgcn_mfma_f32_16x16x32_bf16(ka0, aq[0], acc, 0, 0, 0);
    acc = __builtin_amdgcn_mfma_f32_16x16x32_bf16(ka1, aq[1], acc, 0, 0, 0);
#pragma unroll
    for (int r = 0; r < 4; ++r) {
      float m = (r == 0) ? ma.x : (r == 1) ? ma.y : (r == 2) ? ma.z : ma.w;
      float val = acc[r] + m;  // m already includes -EXPBIAS
      val = ((ua >> (8 * r)) & 0xff) ? -__builtin_inff() : val;
      float e = __expf(val);
      ssum += e;
      pa[st >> 1][4 * (st & 1) + r] = (bf16_t)e;
    }
    ka0 = kb0; ka1 = kb1; ma = mb; ua = ub;
    kb0 = kc0; kb1 = kc1; mb = mc; ub = uc;
  }

  // ---- row sum reduce (t fixed per lane) ----
  ssum += __shfl_xor(ssum, 16, 64);
  ssum += __shfl_xor(ssum, 32, 64);
  if (lane < 16) wsum[lane][w] = ssum;
  __syncthreads();
  float ss = 0.f;
#pragma unroll
  for (int ww = 0; ww < 8; ++ww) ss += wsum[lt][ww];
  const float rl = 1.0f / ss;

  // ---- PV + interleaved transposed weight stores ----
  f32x4 po[4] = {};
  bf16x8 vfa[4], vfb[4];
#pragma unroll
  for (int dt = 0; dt < 4; ++dt)
    vfa[dt] = *(const bf16x8*)&vfrag[(size_t)((w * 8) * 4 + dt) * 512 + lane * 8];
#pragma unroll
  for (int kx = 0; kx < 8; ++kx) {
    if (kx < 7) {
#pragma unroll
      for (int dt = 0; dt < 4; ++dt)
        vfb[dt] = *(const bf16x8*)&vfrag[(size_t)((w * 8 + kx + 1) * 4 + dt) * 512 + lane * 8];
    }
    // stage this kx's normalized weights into per-wave LDS (s-local = 8g+j)
    f32x4 wv0, wv1;
#pragma unroll
    for (int r = 0; r < 4; ++r) { wv0[r] = (float)pa[kx][r] * rl; wv1[r] = (float)pa[kx][4 + r] * rl; }
    *(f32x4*)&sbuf[w][lt][8 * g] = wv0;
    *(f32x4*)&sbuf[w][lt][8 * g + 4] = wv1;
    __builtin_amdgcn_s_setprio(1);
#pragma unroll
    for (int dt = 0; dt < 4; ++dt)
      po[dt] = __builtin_amdgcn_mfma_f32_16x16x32_bf16(vfa[dt], pa[kx], po[dt], 0, 0, 0);
    __builtin_amdgcn_s_setprio(0);
    asm volatile("s_waitcnt lgkmcnt(0)" ::: "memory");
    // read back row-major and store: 8 rows x 128B contiguous per instr
#pragma unroll
    for (int p = 0; p < 2; ++p) {
      int row = 8 * p + (lane >> 3);
      int c4 = (lane & 7) * 4;
      f32x4 rv = *(const f32x4*)&sbuf[w][row][c4];
      __builtin_nontemporal_store(rv,
          (f32x4*)&wrow[(size_t)(t0 + row) * 2048 + s0w + 32 * kx + c4]);
    }
#pragma unroll
    for (int dt = 0; dt < 4; ++dt) vfa[dt] = vfb[dt];
  }
#pragma unroll
  for (int dt = 0; dt < 4; ++dt) po[dt] *= rl;

  // ---- cross-wave reduce of PV partials (O^T layout: row=d, col=t) ----
#pragma unroll
  for (int dt = 0; dt < 4; ++dt) {
    f32x4 v = po[dt];
    *(f32x4*)&pbuf[w][lt][dt * 16 + 4 * g] = v;
  }
  __syncthreads();
  int e0 = threadIdx.x * 2;
  int row = e0 >> 6, d = e0 & 63;
  float v0 = 0.f, v1 = 0.f;
#pragma unroll
  for (int ww = 0; ww < 8; ++ww) {
    v0 += pbuf[ww][row][d];
    v1 += pbuf[ww][row][d + 1];
  }
  int h = bh & 15;
  union { bf16_t hh[2]; uint32_t u; } pk;
  pk.hh[0] = (bf16_t)v0; pk.hh[1] = (bf16_t)v1;
  *(uint32_t*)&X2[(size_t)((t0 + row) * 2 + b) * 1024 + h * 64 + d] = pk.u;
}

// ---------------- launch ----------------
extern "C" void kernel_launch(void* const* d_in, const int* in_sizes, int n_in,
                              void* d_out, int out_size, void* d_ws, size_t ws_size,
                              hipStream_t stream) {
  (void)in_sizes; (void)n_in; (void)out_size; (void)ws_size;
  const float* query = (const float*)d_in[0];
  const uint8_t* kpm = (const uint8_t*)d_in[1];
  const float* amask = (const float*)d_in[2];
  const float* Wq = (const float*)d_in[3];
  const float* bq = (const float*)d_in[4];
  const float* Wk = (const float*)d_in[5];
  const float* bk = (const float*)d_in[6];
  const float* Wv = (const float*)d_in[7];
  const float* bv = (const float*)d_in[8];
  const float* Wo = (const float*)d_in[9];
  const float* bo = (const float*)d_in[10];
  float* dout = (float*)d_out;
  char* ws = (char*)d_ws;

  bf16_t* Xq = (bf16_t*)(ws + WS_XQ);
  bf16_t* Wbf = (bf16_t*)(ws + WS_W);
  bf16_t* qh = (bf16_t*)(ws + WS_QH);
  bf16_t* kh = (bf16_t*)(ws + WS_KH);
  bf16_t* vT = (bf16_t*)(ws + WS_VT);
  bf16_t* X2 = (bf16_t*)(ws + WS_X2);
  float* amF = (float*)(ws + WS_AM);

  prep_kernel<<<12288, 256, 0, stream>>>(query, Wq, Wk, Wv, Wo, amask, Xq, Wbf, amF);
  gemm_nt<<<dim3(8, 32, 3), 256, 0, stream>>>(Xq, X2, Wbf, bq, bk, bv, bo, dout, qh, kh, vT, 0);
  attn_kernel<<<dim3(32, 128), 512, 0, stream>>>(qh, kh, vT, amF, kpm, dout + OFF_WEI, X2);
  gemm_nt<<<dim3(8, 32, 1), 256, 0, stream>>>(Xq, X2, Wbf, bq, bk, bv, bo, dout, qh, kh, vT, 3);
}